// Round 1
// baseline (700.627 us; speedup 1.0000x reference)
//
#include <hip/hip_runtime.h>

#define DTC 0.02f
#define INV_DT_SKIP 2.5f            // 1/(0.02*20)
#define NBLK 32
#define NSTEP 50

typedef __attribute__((ext_vector_type(8))) __bf16 bf16x8;
typedef __attribute__((ext_vector_type(4))) float f32x4;
typedef __attribute__((ext_vector_type(8))) unsigned short us8;
typedef unsigned long long u64t;

__device__ inline unsigned short f2bf(float x) {        // RNE fp32->bf16
    unsigned u = __float_as_uint(x);
    unsigned r = u + 0x7FFF + ((u >> 16) & 1u);
    return (unsigned short)(r >> 16);
}
__device__ inline float bf2f(unsigned short h) {
    return __uint_as_float(((unsigned)h) << 16);
}
// Agent-scoped (cross-XCD, coherence-point) RELAXED accesses. No flags, no
// drains: every transmitted u32 carries a 4-bit step tag in its mantissa
// LSBs, so consumers validate freshness per-word and retry stale loads.
__device__ inline void gstore64(u64t* p, u64t v) {
    __hip_atomic_store(p, v, __ATOMIC_RELAXED, __HIP_MEMORY_SCOPE_AGENT);
}
__device__ inline u64t gload64(const u64t* p) {
    return __hip_atomic_load(p, __ATOMIC_RELAXED, __HIP_MEMORY_SCOPE_AGENT);
}
// Pin a 16B fragment into VGPRs: opaque def prevents the allocator from
// rematerializing the global load + bf16 conversion every loop iteration.
#define PINV(x) asm volatile("" : "+v"(x))

// ---------------------------------------------------------------------------
// Neumann inverses (verified rounds 1-7). inv1 = (I-dt*Ap)^-1,
// inv2 = (3I-2dt*Ap)^-1. Also zeroes pbuf (tag 0 != any live tag 1/2 for the
// first-use steps) so virgin workspace can never validate.
// ---------------------------------------------------------------------------
__global__ __launch_bounds__(256) void kinv(const float* __restrict__ Ap,
                                            float* __restrict__ inv1,
                                            float* __restrict__ inv2,
                                            uint4* __restrict__ pz) {
    const int t = threadIdx.x;
    // zero 2 parities x 32 slots x 2048 u32 = 32768 uint4, split across the
    // 2 blocks; overlaps with the LDS compute below (disjoint memory).
    {
        const int gt = blockIdx.x * 256 + t;
        for (int i = gt; i < 32768; i += 512) pz[i] = (uint4){0u, 0u, 0u, 0u};
    }
    const float coef  = (blockIdx.x == 0) ? DTC : (2.0f * DTC / 3.0f);
    const float scale = (blockIdx.x == 0) ? 1.0f : (1.0f / 3.0f);
    float* outp = (blockIdx.x == 0) ? inv1 : inv2;

    __shared__ float ET[64 * 68];
    __shared__ float XA[64 * 68];
    __shared__ float XB[64 * 68];

    for (int idx = t; idx < 4096; idx += 256) {
        int r = idx >> 6, c = idx & 63;
        float e = coef * Ap[idx];
        ET[c * 68 + r] = e;
        XA[r * 68 + c] = ((r == c) ? 1.0f : 0.0f) + e;
    }
    __syncthreads();

    const int rr = (t >> 4) << 2;
    const int cc = (t & 15) << 2;
    float* bufs[2] = {XA, XB};
    for (int it = 0; it < 3; it++) {
        const float* Xin = bufs[it & 1];
        float* Xout = bufs[(it + 1) & 1];
        float acc[4][4];
        #pragma unroll
        for (int i = 0; i < 4; i++)
            #pragma unroll
            for (int j = 0; j < 4; j++)
                acc[i][j] = ((rr + i) == (cc + j)) ? 1.0f : 0.0f;
        for (int k = 0; k < 64; k++) {
            float4 e4 = *(const float4*)&ET[k * 68 + rr];
            float4 x4 = *(const float4*)&Xin[k * 68 + cc];
            float ev[4] = {e4.x, e4.y, e4.z, e4.w};
            float xv[4] = {x4.x, x4.y, x4.z, x4.w};
            #pragma unroll
            for (int i = 0; i < 4; i++)
                #pragma unroll
                for (int j = 0; j < 4; j++)
                    acc[i][j] += ev[i] * xv[j];
        }
        __syncthreads();
        #pragma unroll
        for (int i = 0; i < 4; i++)
            #pragma unroll
            for (int j = 0; j < 4; j++)
                Xout[(rr + i) * 68 + cc + j] = acc[i][j];
        __syncthreads();
    }
    const float* Xf = bufs[1];
    for (int idx = t; idx < 4096; idx += 256) {
        int r = idx >> 6, c = idx & 63;
        outp[idx] = scale * Xf[r * 68 + c];
    }
}

// ---------------------------------------------------------------------------
// Persistent kernel, 32 blocks. NO flag barrier: partials are transmitted as
// f32 pairs with a 4-bit step tag ((k+1)&15) in each word's mantissa LSBs.
// Per step:
//   Phase A: z = a@W^T hi/lo bf16 MFMA, f=u*dx+v*dy, intra-wave LDS C->A
//   relayout, proj MFMA -> red2 -> sync -> block reduce -> tagged-f32 slot
//   (parity double-buffered, fire-and-forget agent stores) -> rbase hoist
//   (LDS reads hide under gather latency) -> gather 32 slots with per-word
//   tag validation + retry (software-pipelined, 3x4-slot groups in flight)
//   -> f in regs -> BDF2 r -> LDS -> sync -> distributed solve -> sync.
// Tag correctness: parity bounds staleness to step k-2, whose tag (k-1)&15
// always differs from (k+1)&15 (delta 2 mod 16). Torn u64s fail per-word
// validation. WAR: storing step k implies gather k-1 completed, which
// implies (via data dependency partials(k-1) <- f(k-2)) every block consumed
// its k-2 gather, so the parity buffer being overwritten has no readers.
// ---------------------------------------------------------------------------
__global__ __launch_bounds__(512, 2)
void kmain(const float* __restrict__ state,
           const float* __restrict__ Wu,
           const float* __restrict__ Wv,
           const float* __restrict__ Pp,
           const float* __restrict__ inv1,
           const float* __restrict__ inv2,
           unsigned* __restrict__ pbuf,     // 2 parities x 32 slots x 2048 u32
           float* __restrict__ out) {
    const int t = threadIdx.x;
    const int l = t & 63;
    const int w = t >> 6;                 // wave 0..7
    const int blk = blockIdx.x;
    const int gw = blk * 8 + w;           // 0..255
    const bool active = (gw < 250);       // waves 250..255 idle in phase A

    __shared__ float Ab[3][2176];         // a triple buffer, 32 rows x 68
    __shared__ float fb[8][16][36];       // per-wave f tile (K=32 + pad)
    __shared__ float red2[2][8][1024];    // per-mt, per-wave proj partials
    __shared__ float rbuf[32 * 68];       // r, padded stride 68

    for (int i = t; i < 2048; i += 512) Ab[0][(i >> 6) * 68 + (i & 63)] = state[i];
    if (!active) {                        // idle waves' red2 stays zero forever
        for (int i = l; i < 1024; i += 64) { red2[0][w][i] = 0.f; red2[1][w][i] = 0.f; }
    }

    const int nr = l & 15;
    const int c0 = (l >> 4) << 3;
    const int cA = gw * 2;                 // chunk ids (cA,cA+1), same net
    const float* W = (cA < 250) ? Wu : Wv;
    const int glA = ((cA < 250) ? cA : cA - 250) * 32;

    // ---- persistent fragments, pinned into VGPRs ----
    bf16x8 wf[2][2][4][2], pf[2][4], sfw[2];
    if (active) {
        #pragma unroll
        for (int ch = 0; ch < 2; ch++)
            #pragma unroll
            for (int th = 0; th < 2; th++)
                #pragma unroll
                for (int rb = 0; rb < 4; rb++)
                    #pragma unroll
                    for (int kt = 0; kt < 2; kt++) {
                        const float* s = W + (size_t)(rb * 8000 + glA + ch * 32 + th * 16 + nr) * 64
                                           + kt * 32 + c0;
                        us8 o;
                        #pragma unroll
                        for (int j = 0; j < 8; j++) o[j] = f2bf(s[j]);
                        wf[ch][th][rb][kt] = __builtin_bit_cast(bf16x8, o);
                    }
        #pragma unroll
        for (int ch = 0; ch < 2; ch++)
            #pragma unroll
            for (int pt = 0; pt < 4; pt++) {
                const float* s = Pp + (size_t)(pt * 16 + nr) * 16000 + (cA + ch) * 32 + c0;
                us8 o;
                #pragma unroll
                for (int j = 0; j < 8; j++) o[j] = f2bf(s[j]);
                pf[ch][pt] = __builtin_bit_cast(bf16x8, o);
            }
    }
    {   // wave's solve tile: mtS = w>>2, ptS = w&3 ; S = inv2 - I/3
        const int ptS = w & 3;
        #pragma unroll
        for (int kt = 0; kt < 2; kt++) {
            int p = ptS * 16 + nr;
            const float* s = inv2 + (size_t)p * 64 + kt * 32 + c0;
            us8 o;
            #pragma unroll
            for (int j = 0; j < 8; j++) {
                float v = s[j] - ((p == kt * 32 + c0 + j) ? (1.0f / 3.0f) : 0.0f);
                o[j] = f2bf(v);
            }
            sfw[kt] = __builtin_bit_cast(bf16x8, o);
        }
    }
    // pin everything (opaque defs -> no rematerialization inside the loop)
    #pragma unroll
    for (int ch = 0; ch < 2; ch++) {
        #pragma unroll
        for (int th = 0; th < 2; th++)
            #pragma unroll
            for (int rb = 0; rb < 4; rb++)
                #pragma unroll
                for (int kt = 0; kt < 2; kt++) PINV(wf[ch][th][rb][kt]);
        #pragma unroll
        for (int pt = 0; pt < 4; pt++) PINV(pf[ch][pt]);
    }
    PINV(sfw[0]); PINV(sfw[1]);
    __syncthreads();

    int ia_prev = 2, ia_cur = 0, ia_next = 1;
    float fprev[4];                       // f_prev for elems 4t..4t+3

    for (int k = 0; k < NSTEP; k++) {
        const int par = k & 1;
        const unsigned tag = (unsigned)(k + 1) & 15u;
        unsigned* pslot = pbuf + (size_t)par * (NBLK * 2048) + blk * 2048;

        // ================= phase A: rhs partials =================
        if (active) {
            const int col = l & 15, q4 = l >> 4;
            #pragma unroll
            for (int mt = 0; mt < 2; mt++) {
                bf16x8 ahi[2], alo[2];
                {
                    const float* ac = Ab[ia_cur];
                    #pragma unroll
                    for (int kt = 0; kt < 2; kt++) {
                        us8 hv, lv;
                        #pragma unroll
                        for (int j = 0; j < 8; j++) {
                            float x = ac[(mt * 16 + nr) * 68 + kt * 32 + c0 + j];
                            unsigned short h = f2bf(x);
                            hv[j] = h;
                            lv[j] = f2bf(x - bf2f(h));
                        }
                        ahi[kt] = __builtin_bit_cast(bf16x8, hv);
                        alo[kt] = __builtin_bit_cast(bf16x8, lv);
                    }
                }
                f32x4 racc[4] = {{0.f,0.f,0.f,0.f},{0.f,0.f,0.f,0.f},
                                 {0.f,0.f,0.f,0.f},{0.f,0.f,0.f,0.f}};
                #pragma unroll
                for (int ch = 0; ch < 2; ch++) {
                    #pragma unroll
                    for (int th = 0; th < 2; th++) {
                        f32x4 z[4];
                        #pragma unroll
                        for (int rb = 0; rb < 4; rb++) {
                            f32x4 acc = {0.f, 0.f, 0.f, 0.f};
                            #pragma unroll
                            for (int kt = 0; kt < 2; kt++) {
                                acc = __builtin_amdgcn_mfma_f32_16x16x32_bf16(ahi[kt], wf[ch][th][rb][kt], acc, 0, 0, 0);
                                acc = __builtin_amdgcn_mfma_f32_16x16x32_bf16(alo[kt], wf[ch][th][rb][kt], acc, 0, 0, 0);
                            }
                            z[rb] = acc;
                        }
                        #pragma unroll
                        for (int r = 0; r < 4; r++) {
                            float f = z[0][r] * z[2][r] + z[1][r] * z[3][r];
                            fb[w][q4 * 4 + r][th * 16 + col] = f;   // intra-wave only
                        }
                    }
                    bf16x8 ff;
                    {
                        us8 fv8;
                        #pragma unroll
                        for (int j = 0; j < 8; j++) fv8[j] = f2bf(fb[w][nr][c0 + j]);
                        ff = __builtin_bit_cast(bf16x8, fv8);
                    }
                    #pragma unroll
                    for (int pt = 0; pt < 4; pt++)
                        racc[pt] = __builtin_amdgcn_mfma_f32_16x16x32_bf16(ff, pf[ch][pt], racc[pt], 0, 0, 0);
                }
                #pragma unroll
                for (int pt = 0; pt < 4; pt++)
                    #pragma unroll
                    for (int r = 0; r < 4; r++)
                        red2[mt][w][(q4 * 4 + r) * 64 + pt * 16 + col] = racc[pt][r];
            }
        }
        __syncthreads();

        // block partial (2048 elems) -> tagged f32 pairs, one slot.
        // Fire-and-forget: no drain, no flag, no barrier. The tag IS the flag.
        {
            u64t* ps64 = (u64t*)pslot;
            #pragma unroll
            for (int mt = 0; mt < 2; mt++) {
                float s0 = 0.f, s1 = 0.f;
                #pragma unroll
                for (int w8 = 0; w8 < 8; w8++) {
                    s0 += red2[mt][w8][2 * t];
                    s1 += red2[mt][w8][2 * t + 1];
                }
                unsigned u0 = (__float_as_uint(s0) & ~15u) | tag;
                unsigned u1 = (__float_as_uint(s1) & ~15u) | tag;
                gstore64(&ps64[mt * 512 + t], (u64t)u0 | ((u64t)u1 << 32));
            }
        }

        // rbase hoist: LDS reads + VALU hide under the gather's load latency
        float rb_[4];
        const int bB = (4 * t) >> 6, p0B = (4 * t) & 63;
        {
            #pragma unroll
            for (int jj = 0; jj < 4; jj++) {
                int row = bB * 68 + p0B + jj;
                float av = Ab[ia_cur][row];
                rb_[jj] = (k == 0) ? av
                                   : (4.f * av - Ab[ia_prev][row] - 2.f * DTC * fprev[jj]);
            }
        }

        // ===== gather: 32 slots, per-word tag validation, pipelined =====
        float fv[4];
        {
            const u64t* pb = (const u64t*)(pbuf + (size_t)par * (NBLK * 2048));
            float s0 = 0.f, s1 = 0.f, s2 = 0.f, s3 = 0.f;
            unsigned need = 0xFFFFFFFFu;

            u64t b0[8], b1[8], b2[8];   // 3 groups x (4 slots x 2 u64) in flight

            #define GISSUE(g, B)                                               \
                _Pragma("unroll")                                              \
                for (int si = 0; si < 4; si++) {                               \
                    const u64t* p = pb + (size_t)((g) * 4 + si) * 1024 + 2 * t;\
                    B[2 * si]     = gload64(p);                                \
                    B[2 * si + 1] = gload64(p + 1);                            \
                }
            #define GVALID(g, B)                                               \
                _Pragma("unroll")                                              \
                for (int si = 0; si < 4; si++) {                               \
                    unsigned a0 = (unsigned)B[2 * si];                         \
                    unsigned a1 = (unsigned)(B[2 * si] >> 32);                 \
                    unsigned d0 = (unsigned)B[2 * si + 1];                     \
                    unsigned d1 = (unsigned)(B[2 * si + 1] >> 32);             \
                    unsigned bad = ((a0 ^ tag) | (a1 ^ tag) |                  \
                                    (d0 ^ tag) | (d1 ^ tag)) & 15u;            \
                    if (bad == 0u) {                                           \
                        s0 += __uint_as_float(a0 & ~15u);                      \
                        s1 += __uint_as_float(a1 & ~15u);                      \
                        s2 += __uint_as_float(d0 & ~15u);                      \
                        s3 += __uint_as_float(d1 & ~15u);                      \
                        need &= ~(1u << ((g) * 4 + si));                       \
                    }                                                          \
                }

            GISSUE(0, b0); GISSUE(1, b1); GISSUE(2, b2);
            GVALID(0, b0); GISSUE(3, b0);
            GVALID(1, b1); GISSUE(4, b1);
            GVALID(2, b2); GISSUE(5, b2);
            GVALID(3, b0); GISSUE(6, b0);
            GVALID(4, b1); GISSUE(7, b1);
            GVALID(5, b2);
            GVALID(6, b0);
            GVALID(7, b1);

            // straggler retry (rare; period ~= one coherence round trip)
            while (need) {
                #pragma unroll
                for (int sl = 0; sl < 32; sl++) {
                    if (need & (1u << sl)) {
                        const u64t* p = pb + (size_t)sl * 1024 + 2 * t;
                        u64t v0 = gload64(p), v1 = gload64(p + 1);
                        unsigned a0 = (unsigned)v0, a1 = (unsigned)(v0 >> 32);
                        unsigned d0 = (unsigned)v1, d1 = (unsigned)(v1 >> 32);
                        unsigned bad = ((a0 ^ tag) | (a1 ^ tag) |
                                        (d0 ^ tag) | (d1 ^ tag)) & 15u;
                        if (bad == 0u) {
                            s0 += __uint_as_float(a0 & ~15u);
                            s1 += __uint_as_float(a1 & ~15u);
                            s2 += __uint_as_float(d0 & ~15u);
                            s3 += __uint_as_float(d1 & ~15u);
                            need &= ~(1u << sl);
                        }
                    }
                }
            }
            #undef GISSUE
            #undef GVALID
            asm volatile("" ::: "memory");
            fv[0] = -s0; fv[1] = -s1; fv[2] = -s2; fv[3] = -s3;
        }

        // ================= phase B: BDF2 combine + distributed solve =================
        {
            const float cf = (k == 0) ? DTC : 4.f * DTC;
            #pragma unroll
            for (int jj = 0; jj < 4; jj++) {
                float f = fv[jj];
                rbuf[bB * 68 + p0B + jj] = rb_[jj] + cf * f;
                fprev[jj] = f;
            }
        }
        __syncthreads();

        {   // wave (mtS = w>>2, ptS = w&3): a_next tile = cb*r + (r @ S^T) tile
            const int mtS = w >> 2, ptS = w & 3;
            const int col = l & 15, q4 = l >> 4;
            bf16x8 S0, S1;
            float cb;
            if (k == 0) {                   // S1 = inv1 - I, cb = 1 (once)
                #pragma unroll
                for (int kt = 0; kt < 2; kt++) {
                    int p = ptS * 16 + nr;
                    const float* s = inv1 + (size_t)p * 64 + kt * 32 + c0;
                    us8 o;
                    #pragma unroll
                    for (int j = 0; j < 8; j++) {
                        float v = s[j] - ((p == kt * 32 + c0 + j) ? 1.0f : 0.0f);
                        o[j] = f2bf(v);
                    }
                    if (kt == 0) S0 = __builtin_bit_cast(bf16x8, o);
                    else         S1 = __builtin_bit_cast(bf16x8, o);
                }
                cb = 1.0f;
            } else {
                S0 = sfw[0]; S1 = sfw[1];
                cb = 1.0f / 3.0f;
            }
            bf16x8 rhi[2], rlo[2];
            #pragma unroll
            for (int kt = 0; kt < 2; kt++) {
                us8 hv, lv;
                #pragma unroll
                for (int j = 0; j < 8; j++) {
                    float x = rbuf[(mtS * 16 + nr) * 68 + kt * 32 + c0 + j];
                    unsigned short h = f2bf(x);
                    hv[j] = h;
                    lv[j] = f2bf(x - bf2f(h));
                }
                rhi[kt] = __builtin_bit_cast(bf16x8, hv);
                rlo[kt] = __builtin_bit_cast(bf16x8, lv);
            }
            f32x4 acc;
            #pragma unroll
            for (int r = 0; r < 4; r++)
                acc[r] = rbuf[(mtS * 16 + q4 * 4 + r) * 68 + ptS * 16 + col] * cb;
            acc = __builtin_amdgcn_mfma_f32_16x16x32_bf16(rhi[0], S0, acc, 0, 0, 0);
            acc = __builtin_amdgcn_mfma_f32_16x16x32_bf16(rlo[0], S0, acc, 0, 0, 0);
            acc = __builtin_amdgcn_mfma_f32_16x16x32_bf16(rhi[1], S1, acc, 0, 0, 0);
            acc = __builtin_amdgcn_mfma_f32_16x16x32_bf16(rlo[1], S1, acc, 0, 0, 0);
            #pragma unroll
            for (int r = 0; r < 4; r++)
                Ab[ia_next][(mtS * 16 + q4 * 4 + r) * 68 + ptS * 16 + col] = acc[r];
        }
        __syncthreads();

        if (k == NSTEP - 1 && blk == 0) {
            for (int i = t; i < 2048; i += 512)
                out[i] = (Ab[ia_next][(i >> 6) * 68 + (i & 63)] - state[i]) * INV_DT_SKIP;
        }

        int tmp = ia_prev; ia_prev = ia_cur; ia_cur = ia_next; ia_next = tmp;
    }
}

// ---------------------------------------------------------------------------
extern "C" void kernel_launch(void* const* d_in, const int* in_sizes, int n_in,
                              void* d_out, int out_size, void* d_ws, size_t ws_size,
                              hipStream_t stream) {
    const float* state = (const float*)d_in[0];   // (32, 64)
    const float* Ap    = (const float*)d_in[1];   // (64, 64)
    const float* Wu    = (const float*)d_in[2];   // (32000, 64)
    const float* Wv    = (const float*)d_in[3];   // (32000, 64)
    const float* Pp    = (const float*)d_in[4];   // (64, 16000)
    float* out = (float*)d_out;
    float* ws  = (float*)d_ws;

    float* inv1 = ws;                               // 4096 floats
    float* inv2 = ws + 4096;                        // 4096 floats
    unsigned* pbuf = (unsigned*)(ws + 8192);        // 2 x 32 x 2048 u32 (tagged f32)

    hipLaunchKernelGGL(kinv, dim3(2), dim3(256), 0, stream, Ap, inv1, inv2,
                       (uint4*)pbuf);
    hipLaunchKernelGGL(kmain, dim3(NBLK), dim3(512), 0, stream,
                       state, Wu, Wv, Pp, inv1, inv2, pbuf, out);
}